// Round 1
// baseline (250.350 us; speedup 1.0000x reference)
//
#include <hip/hip_runtime.h>

// SIREN hypernetwork: N=16 samples, each with private (base+offset) weights.
// Kernel 1 (siren_pre): W_eff = ws_h + offset, transposed -> f16 Wt[e][k] in ws.
// Kernel 2 (siren_main): per block = (sample, 128-point tile); layer0 in fp32
// (OMEGA=30 amplifies rounding), hidden layers f16 MFMA 16x16x32 with swapped
// operands (A=W^T, B=H^T) so D-frags pack straight into row-major H (ds_write_b64).
// LDS XOR-swizzle (byte ^= (row&7)<<4) on H and W tiles; W staged with
// global_load_lds width=16, source pre-swizzled, double-buffered 2-phase.

#define N_S 16
#define HW_S 16384
#define E_S 263936
#define OMEGA_F 30.0f

typedef _Float16 f16x8 __attribute__((ext_vector_type(8)));
typedef _Float16 f16x4 __attribute__((ext_vector_type(4)));
typedef _Float16 f16x2 __attribute__((ext_vector_type(2)));
typedef float f32x4 __attribute__((ext_vector_type(4)));

// ws layout (bytes)
#define WT_OFF   0u          // f16 [16][4][256][256]  (8388608 B)
#define W0T_OFF  8388608u    // f32 [16][256][2]       (32768 B)
#define B0_OFF   8421376u    // f32 [16][256]          (16384 B)
#define BE_OFF   8437760u    // f32 [16][4][256]       (65536 B)
// total 8503296 B

__global__ __launch_bounds__(256) void siren_pre(
    const float* __restrict__ wo, const float* __restrict__ w0,
    const float* __restrict__ b0, const float* __restrict__ wsh,
    const float* __restrict__ bsh, char* __restrict__ ws)
{
  __shared__ float tile[64][65];
  int b = blockIdx.x, t = threadIdx.x;
  if (b < 1024) {
    // transpose-convert one 64k x 64e tile of layer-l, sample-n weights
    int n = b >> 6, rem = b & 63, l = rem >> 4, sub = rem & 15;
    int tk = sub >> 2, te = sub & 3;
    int e_loc = t & 63, ksub = t >> 6;
    const float* wo_n = wo + (size_t)n * E_S + 768 + l * 65792;
    const float* wsh_l = wsh + l * 65536;
    for (int r = 0; r < 16; ++r) {
      int k_loc = ksub * 16 + r;
      int k = tk * 64 + k_loc, e = te * 64 + e_loc;
      tile[k_loc][e_loc] = wsh_l[k * 256 + e] + wo_n[k * 256 + e];
    }
    __syncthreads();
    _Float16* wt = (_Float16*)(ws + WT_OFF) + (size_t)(n * 4 + l) * 65536;
    int kp = (t & 31) * 2, esub = t >> 5;
    for (int r = 0; r < 8; ++r) {
      int e_loc2 = esub * 8 + r;
      f16x2 hv = { (_Float16)tile[kp][e_loc2], (_Float16)tile[kp + 1][e_loc2] };
      int e = te * 64 + e_loc2, k = tk * 64 + kp;
      *(f16x2*)(wt + (size_t)e * 256 + k) = hv;
    }
  } else if (b == 1024) {
    float* w0t = (float*)(ws + W0T_OFF);
    float* b0e = (float*)(ws + B0_OFF);
    for (int idx = t; idx < 4096; idx += 256) {
      int n = idx >> 8, e = idx & 255;
      const float* wo_n = wo + (size_t)n * E_S;
      float2 v;
      v.x = w0[e] + wo_n[e];
      v.y = w0[256 + e] + wo_n[256 + e];
      *(float2*)(w0t + (n * 256 + e) * 2) = v;
      b0e[n * 256 + e] = b0[e] + wo_n[512 + e];
    }
  } else {
    float* be = (float*)(ws + BE_OFF);
    for (int idx = t; idx < 16384; idx += 256) {
      int n = idx >> 10, rem = idx & 1023, l = rem >> 8, e = rem & 255;
      be[(n * 4 + l) * 256 + e] =
          bsh[l * 256 + e] + wo[(size_t)n * E_S + 768 + l * 65792 + 65536 + e];
    }
  }
}

__global__ __launch_bounds__(256, 1) void siren_main(
    const float* __restrict__ x, const char* __restrict__ ws,
    const float* __restrict__ w_out, const float* __restrict__ b_out,
    const float* __restrict__ out_scale, float* __restrict__ out)
{
  __shared__ __align__(16) unsigned char sH[65536];      // H[128 p][256 e] f16, swizzled
  __shared__ __align__(16) unsigned char sW[2][32768];   // Wc[256 e][64 k] f16, swizzled
  // overlay (only used after last chunk, which reads sW[1]):
  float* sWout = (float*)sW[0];                          // [256][3] f32
  float (*sRed)[3] = (float(*)[3])(sW[0] + 3072);        // [2][128][3] f32

  int tid = threadIdx.x;
  int lane = tid & 63, wave = tid >> 6;
  int g = lane >> 4, li = lane & 15;
  int we = wave & 1, wp = wave >> 1;
  int bid = blockIdx.x;
  int n = bid & 15, tile = bid >> 4;   // sample n -> XCD n%8 (L2 locality)

  const char* wt_n = ws + WT_OFF + (size_t)n * 4 * 131072;

  // ---- prologue: stage (l=0,c=0) into sW[0] (linear dest, pre-swizzled src)
  {
    int kslot = (lane & 7) ^ (lane >> 3);
    const char* src0 = wt_n + (size_t)(lane >> 3) * 512 + kslot * 16;
#pragma unroll
    for (int s = 0; s < 8; ++s) {
      int i = wave * 8 + s;
      __builtin_amdgcn_global_load_lds(
          (const __attribute__((address_space(1))) unsigned int*)(src0 + (size_t)i * 4096),
          (__attribute__((address_space(3))) unsigned int*)(&sW[0][i * 1024]),
          16, 0, 0);
    }
  }

  // ---- first layer in fp32 (OMEGA amplifies rounding 30x)
  {
    const float* xp = x + ((size_t)n * HW_S + (size_t)tile * 128) * 2;
    const float* w0t = (const float*)(ws + W0T_OFF) + n * 512;
    const float* b0e = (const float*)(ws + B0_OFF) + n * 256;
    int p = tid & 127;
    float x0 = xp[p * 2], x1 = xp[p * 2 + 1];
    int swz = (p & 7) << 4;
    unsigned char* hrow = sH + p * 512;
    for (int it = 0; it < 32; ++it) {
      int eg = (tid >> 7) + it * 2;   // 0..63
      int e0 = eg * 4;
      f32x4 wA = *(const f32x4*)(w0t + e0 * 2);
      f32x4 wB = *(const f32x4*)(w0t + e0 * 2 + 4);
      f32x4 bv = *(const f32x4*)(b0e + e0);
      f16x4 hv;
      hv[0] = (_Float16)__sinf(OMEGA_F * fmaf(x1, wA[1], fmaf(x0, wA[0], bv[0])));
      hv[1] = (_Float16)__sinf(OMEGA_F * fmaf(x1, wA[3], fmaf(x0, wA[2], bv[1])));
      hv[2] = (_Float16)__sinf(OMEGA_F * fmaf(x1, wB[1], fmaf(x0, wB[0], bv[2])));
      hv[3] = (_Float16)__sinf(OMEGA_F * fmaf(x1, wB[3], fmaf(x0, wB[2], bv[3])));
      *(f16x4*)(hrow + ((eg * 8) ^ swz)) = hv;
    }
  }
  __syncthreads();

  const float* be_n = (const float*)(ws + BE_OFF) + n * 4 * 256;
  int liswz = (li & 7) << 4;

  for (int l = 0; l < 4; ++l) {
    f32x4 acc[8][4];
#pragma unroll
    for (int et = 0; et < 8; ++et)
#pragma unroll
      for (int pt = 0; pt < 4; ++pt) acc[et][pt] = (f32x4){0.f, 0.f, 0.f, 0.f};

    for (int c = 0; c < 4; ++c) {
      int q = l * 4 + c;
      if (q < 15) {  // stage next chunk into other buffer
        int qn = q + 1;
        int kslot = (lane & 7) ^ (lane >> 3);
        const char* src0 = wt_n + (size_t)(qn >> 2) * 131072 +
                           (size_t)(lane >> 3) * 512 + (qn & 3) * 128 + kslot * 16;
        unsigned char* dst = sW[qn & 1];
#pragma unroll
        for (int s = 0; s < 8; ++s) {
          int i = wave * 8 + s;
          __builtin_amdgcn_global_load_lds(
              (const __attribute__((address_space(1))) unsigned int*)(src0 + (size_t)i * 4096),
              (__attribute__((address_space(3))) unsigned int*)(dst + i * 1024),
              16, 0, 0);
        }
      }
      const unsigned char* Wb = sW[q & 1];
#pragma unroll
      for (int ks = 0; ks < 2; ++ks) {
        int koffB = c * 128 + ks * 64 + g * 16;
        f16x8 bfr[4];
#pragma unroll
        for (int pt = 0; pt < 4; ++pt) {
          int p = (wp * 4 + pt) * 16 + li;
          bfr[pt] = *(const f16x8*)(sH + p * 512 + (koffB ^ ((p & 7) << 4)));
        }
        int koffA = ks * 64 + g * 16;
#pragma unroll
        for (int et = 0; et < 8; ++et) {
          int e = (we * 8 + et) * 16 + li;
          f16x8 afr = *(const f16x8*)(Wb + e * 128 + (koffA ^ liswz));
#pragma unroll
          for (int pt = 0; pt < 4; ++pt)
            acc[et][pt] = __builtin_amdgcn_mfma_f32_16x16x32_f16(afr, bfr[pt], acc[et][pt], 0, 0, 0);
        }
      }
      __syncthreads();  // staged data drained (vmcnt) + reads of cur done
    }

    if (l < 3) {
      const float* bias = be_n + l * 256;
#pragma unroll
      for (int et = 0; et < 8; ++et) {
        int ecol = we * 8 + et;
        f32x4 bv = *(const f32x4*)(bias + ecol * 16 + g * 4);
#pragma unroll
        for (int pt = 0; pt < 4; ++pt) {
          int p = (wp * 4 + pt) * 16 + li;
          f16x4 hv;
#pragma unroll
          for (int r = 0; r < 4; ++r)
            hv[r] = (_Float16)__sinf(acc[et][pt][r] + bv[r]);
          *(f16x4*)(sH + p * 512 + ((ecol * 32 + g * 8) ^ ((p & 7) << 4))) = hv;
        }
      }
      __syncthreads();
    } else {
      // final: h = sin(z), out = (h @ w_out + b_out) * out_scale
      for (int i2 = tid; i2 < 768; i2 += 256) sWout[i2] = w_out[i2];
      __syncthreads();
      const float* bias = be_n + l * 256;
      float part[4][3];
#pragma unroll
      for (int pt = 0; pt < 4; ++pt)
#pragma unroll
        for (int co = 0; co < 3; ++co) part[pt][co] = 0.f;
#pragma unroll
      for (int et = 0; et < 8; ++et) {
        int ecol = we * 8 + et;
        f32x4 bv = *(const f32x4*)(bias + ecol * 16 + g * 4);
#pragma unroll
        for (int r = 0; r < 4; ++r) {
          int e = ecol * 16 + g * 4 + r;
          float wc0 = sWout[e * 3 + 0], wc1 = sWout[e * 3 + 1], wc2 = sWout[e * 3 + 2];
#pragma unroll
          for (int pt = 0; pt < 4; ++pt) {
            float h = __sinf(acc[et][pt][r] + bv[r]);
            part[pt][0] = fmaf(h, wc0, part[pt][0]);
            part[pt][1] = fmaf(h, wc1, part[pt][1]);
            part[pt][2] = fmaf(h, wc2, part[pt][2]);
          }
        }
      }
#pragma unroll
      for (int pt = 0; pt < 4; ++pt)
#pragma unroll
        for (int co = 0; co < 3; ++co) {
          float v = part[pt][co];
          v += __shfl_xor(v, 16);
          v += __shfl_xor(v, 32);
          part[pt][co] = v;
        }
      if (g == 0) {
#pragma unroll
        for (int pt = 0; pt < 4; ++pt) {
          int p = (wp * 4 + pt) * 16 + li;
          sRed[we * 128 + p][0] = part[pt][0];
          sRed[we * 128 + p][1] = part[pt][1];
          sRed[we * 128 + p][2] = part[pt][2];
        }
      }
      __syncthreads();
      if (tid < 128) {
        int p = tid;
        size_t o = ((size_t)n * HW_S + (size_t)tile * 128 + p) * 3;
#pragma unroll
        for (int co = 0; co < 3; ++co)
          out[o + co] = (sRed[0 * 128 + p][co] + sRed[1 * 128 + p][co] + b_out[co]) * out_scale[co];
      }
    }
  }
}

extern "C" void kernel_launch(void* const* d_in, const int* in_sizes, int n_in,
                              void* d_out, int out_size, void* d_ws, size_t ws_size,
                              hipStream_t stream) {
  const float* x        = (const float*)d_in[0];
  const float* wo       = (const float*)d_in[1];
  const float* w0       = (const float*)d_in[2];
  const float* b0       = (const float*)d_in[3];
  const float* wsh      = (const float*)d_in[4];
  const float* bsh      = (const float*)d_in[5];
  const float* w_out    = (const float*)d_in[6];
  const float* b_out    = (const float*)d_in[7];
  const float* oscale   = (const float*)d_in[8];
  float* out = (float*)d_out;
  char* ws = (char*)d_ws;

  siren_pre<<<1026, 256, 0, stream>>>(wo, w0, b0, wsh, bsh, ws);
  siren_main<<<2048, 256, 0, stream>>>(x, ws, w_out, b_out, oscale, out);
}

// Round 2
// 184.962 us; speedup vs baseline: 1.3535x; 1.3535x over previous
//
#include <hip/hip_runtime.h>

// SIREN hypernetwork, round 2.
// siren_pre: W_eff = (ws_h + offset) * (1/2pi), transposed & K=32-chunk-contiguous
//            f16 layout [n][l][c][e][k] so main-kernel staging is a linear copy.
//            Layer-0 / bias tables pre-scaled so sin(z) == v_sin(fract(acc)).
// siren_main: 1024 blocks = 16 samples x 64 tiles of 256 points, 512 threads
//            (8 waves: we{2} x wp{4}, et=8, pt=4 -> 0.375 KB LDS-read per MFMA).
//            sH 128K (H, XOR-swizzled rows), sW 16K single-buffer with register
//            prefetch (T14). Bias pre-loaded into accumulators. 2 waves/SIMD.

#define N_S 16
#define HW_S 16384
#define E_S 263936
#define INV2PI 0.15915494309189535f
#define OM2PI  4.774648292756860f   // 30/(2pi)

typedef _Float16 f16x8 __attribute__((ext_vector_type(8)));
typedef _Float16 f16x4 __attribute__((ext_vector_type(4)));
typedef _Float16 f16x2 __attribute__((ext_vector_type(2)));
typedef float f32x4 __attribute__((ext_vector_type(4)));

// ws layout (bytes)
#define WT_OFF   0u          // f16 [16][4][8 chunks][256 e][32 k]  (8388608 B)
#define W0T_OFF  8388608u    // f32 [16][256][2]  * 30/2pi          (32768 B)
#define B0_OFF   8421376u    // f32 [16][256]     * 30/2pi          (16384 B)
#define BE_OFF   8437760u    // f32 [16][4][256]  * 1/2pi           (65536 B)

__device__ __forceinline__ float fsin(float z) {
  return __builtin_amdgcn_sinf(__builtin_amdgcn_fractf(z));
}

__global__ __launch_bounds__(256) void siren_pre(
    const float* __restrict__ wo, const float* __restrict__ w0,
    const float* __restrict__ b0, const float* __restrict__ wsh,
    const float* __restrict__ bsh, char* __restrict__ ws)
{
  __shared__ float tile[64][65];
  int b = blockIdx.x, t = threadIdx.x;
  if (b < 1024) {
    // transpose-convert one 64k x 64e tile of layer-l, sample-n weights
    int n = b >> 6, rem = b & 63, l = rem >> 4, sub = rem & 15;
    int tk = sub >> 2, te = sub & 3;
    int e_loc = t & 63, ksub = t >> 6;
    const float* wo_n = wo + (size_t)n * E_S + 768 + l * 65792;
    const float* wsh_l = wsh + l * 65536;
    for (int r = 0; r < 16; ++r) {
      int k_loc = ksub * 16 + r;
      int k = tk * 64 + k_loc, e = te * 64 + e_loc;
      tile[k_loc][e_loc] = (wsh_l[k * 256 + e] + wo_n[k * 256 + e]) * INV2PI;
    }
    __syncthreads();
    _Float16* wtl = (_Float16*)(ws + WT_OFF) + (size_t)(n * 4 + l) * 65536;
    int kp = (t & 31) * 2, esub = t >> 5;
    for (int r = 0; r < 8; ++r) {
      int e_loc2 = esub * 8 + r;
      f16x2 hv;
      hv[0] = (_Float16)tile[kp][e_loc2];
      hv[1] = (_Float16)tile[kp + 1][e_loc2];
      int e = te * 64 + e_loc2, k = tk * 64 + kp;
      int c = k >> 5, kin = k & 31;
      *(f16x2*)(wtl + (size_t)c * 8192 + e * 32 + kin) = hv;
    }
  } else if (b == 1024) {
    float* w0t = (float*)(ws + W0T_OFF);
    float* b0e = (float*)(ws + B0_OFF);
    for (int idx = t; idx < 4096; idx += 256) {
      int n = idx >> 8, e = idx & 255;
      const float* wo_n = wo + (size_t)n * E_S;
      float2 v;
      v.x = (w0[e] + wo_n[e]) * OM2PI;
      v.y = (w0[256 + e] + wo_n[256 + e]) * OM2PI;
      *(float2*)(w0t + (n * 256 + e) * 2) = v;
      b0e[n * 256 + e] = (b0[e] + wo_n[512 + e]) * OM2PI;
    }
  } else {
    float* be = (float*)(ws + BE_OFF);
    for (int idx = t; idx < 16384; idx += 256) {
      int n = idx >> 10, rem = idx & 1023, l = rem >> 8, e = rem & 255;
      be[(n * 4 + l) * 256 + e] =
          (bsh[l * 256 + e] + wo[(size_t)n * E_S + 768 + l * 65792 + 65536 + e]) * INV2PI;
    }
  }
}

__global__ __launch_bounds__(512, 2) void siren_main(
    const float* __restrict__ x, const char* __restrict__ ws,
    const float* __restrict__ w_out, const float* __restrict__ b_out,
    const float* __restrict__ out_scale, float* __restrict__ out)
{
  __shared__ __align__(16) unsigned char sH[131072];  // H[256 p][256 e] f16, row-XOR-swizzled
  __shared__ __align__(16) unsigned char sW[16384];   // W chunk [256 e][32 k] f16, slot-swizzled

  int tid = threadIdx.x;
  int lane = tid & 63, wave = tid >> 6;
  int g = lane >> 4, li = lane & 15;
  int we = wave & 1, wp = wave >> 1;     // e-half, p-quarter
  int bid = blockIdx.x;
  int n = bid & 15, tile = bid >> 4;     // sample n -> XCD n&7 (L2 locality)

  const char* wt_n = ws + WT_OFF + (size_t)n * 32 * 16384;

  // register prefetch of chunk 0 (lands under layer-0 compute)
  float4 r0, r1;
  {
    const float4* src = (const float4*)wt_n;
    r0 = src[tid];
    r1 = src[tid + 512];
  }

  // ---- layer 0 in fp32 (weights pre-scaled by 30/2pi) -> sH
  {
    const float* xp = x + ((size_t)n * HW_S + (size_t)tile * 256) * 2;
    int p = tid & 255;
    float2 xv = *(const float2*)(xp + p * 2);
    const float* w0t = (const float*)(ws + W0T_OFF) + n * 512;
    const float* b0e = (const float*)(ws + B0_OFF) + n * 256;
    int swz = (p & 7) << 4;
    unsigned char* hrow = sH + p * 512;
#pragma unroll
    for (int it = 0; it < 16; ++it) {
      int eg = (tid >> 8) * 16 + it;   // 0..31, wave-uniform
      int e0 = eg * 8;
      f32x4 wa = *(const f32x4*)(w0t + e0 * 2);
      f32x4 wb = *(const f32x4*)(w0t + e0 * 2 + 4);
      f32x4 wc = *(const f32x4*)(w0t + e0 * 2 + 8);
      f32x4 wd = *(const f32x4*)(w0t + e0 * 2 + 12);
      f32x4 ba = *(const f32x4*)(b0e + e0);
      f32x4 bb = *(const f32x4*)(b0e + e0 + 4);
      f16x8 hv;
      hv[0] = (_Float16)fsin(fmaf(xv.y, wa[1], fmaf(xv.x, wa[0], ba[0])));
      hv[1] = (_Float16)fsin(fmaf(xv.y, wa[3], fmaf(xv.x, wa[2], ba[1])));
      hv[2] = (_Float16)fsin(fmaf(xv.y, wb[1], fmaf(xv.x, wb[0], ba[2])));
      hv[3] = (_Float16)fsin(fmaf(xv.y, wb[3], fmaf(xv.x, wb[2], ba[3])));
      hv[4] = (_Float16)fsin(fmaf(xv.y, wc[1], fmaf(xv.x, wc[0], bb[0])));
      hv[5] = (_Float16)fsin(fmaf(xv.y, wc[3], fmaf(xv.x, wc[2], bb[1])));
      hv[6] = (_Float16)fsin(fmaf(xv.y, wd[1], fmaf(xv.x, wd[0], bb[2])));
      hv[7] = (_Float16)fsin(fmaf(xv.y, wd[3], fmaf(xv.x, wd[2], bb[3])));
      *(f16x8*)(hrow + ((eg * 16) ^ swz)) = hv;
    }
  }
  // write chunk 0 into sW (swizzled), then sync
  {
    int e0 = tid >> 2, sl = tid & 3, e1 = 128 + e0;
    *(float4*)(sW + e0 * 64 + ((sl ^ (e0 & 3)) << 4)) = r0;
    *(float4*)(sW + e1 * 64 + ((sl ^ (e1 & 3)) << 4)) = r1;
  }
  __syncthreads();

  const float* be_n = (const float*)(ws + BE_OFF) + n * 1024;
  f32x4 acc[8][4];

  for (int l = 0; l < 4; ++l) {
    // bias -> accumulators
    const float* bias = be_n + l * 256;
#pragma unroll
    for (int et = 0; et < 8; ++et) {
      f32x4 bv = *(const f32x4*)(bias + (we * 8 + et) * 16 + g * 4);
#pragma unroll
      for (int pt = 0; pt < 4; ++pt) acc[et][pt] = bv;
    }
    for (int c = 0; c < 8; ++c) {
      int step = l * 8 + c;
      if (step < 31) {  // prefetch next chunk into registers
        const float4* src = (const float4*)(wt_n + (size_t)(step + 1) * 16384);
        r0 = src[tid];
        r1 = src[tid + 512];
      }
      f16x8 bfr[4];
#pragma unroll
      for (int pt = 0; pt < 4; ++pt) {
        int p = (wp * 4 + pt) * 16 + li;
        bfr[pt] = *(const f16x8*)(sH + p * 512 + ((c * 64 + g * 16) ^ ((p & 7) << 4)));
      }
#pragma unroll
      for (int et = 0; et < 8; ++et) {
        int e = (we * 8 + et) * 16 + li;
        f16x8 afr = *(const f16x8*)(sW + e * 64 + ((g ^ (li & 3)) << 4));
#pragma unroll
        for (int pt = 0; pt < 4; ++pt)
          acc[et][pt] = __builtin_amdgcn_mfma_f32_16x16x32_f16(afr, bfr[pt], acc[et][pt], 0, 0, 0);
      }
      __syncthreads();           // all waves done reading sW (and sH for this c)
      if (step < 31) {           // write prefetched chunk (compiler waits vmcnt on r0/r1)
        int e0 = tid >> 2, sl = tid & 3, e1 = 128 + e0;
        *(float4*)(sW + e0 * 64 + ((sl ^ (e0 & 3)) << 4)) = r0;
        *(float4*)(sW + e1 * 64 + ((sl ^ (e1 & 3)) << 4)) = r1;
      }
      if (c == 7 && l < 3) {     // sin + store H for next layer
#pragma unroll
        for (int et = 0; et < 8; ++et) {
          int ecol = we * 8 + et;
#pragma unroll
          for (int pt = 0; pt < 4; ++pt) {
            int p = (wp * 4 + pt) * 16 + li;
            f16x4 hv;
#pragma unroll
            for (int r = 0; r < 4; ++r)
              hv[r] = (_Float16)fsin(acc[et][pt][r]);
            *(f16x4*)(sH + p * 512 + ((ecol * 32 + g * 8) ^ ((p & 7) << 4))) = hv;
          }
        }
      }
      __syncthreads();           // sW + sH updates visible
    }
  }

  // ---- epilogue: h = sin(acc), out = (h @ w_out + b_out) * out_scale
  float* sWf = (float*)sW;       // w_out staging [256][3]
  for (int i = tid; i < 768; i += 512) sWf[i] = w_out[i];
  __syncthreads();

  float part[4][3];
#pragma unroll
  for (int pt = 0; pt < 4; ++pt)
#pragma unroll
    for (int co = 0; co < 3; ++co) part[pt][co] = 0.f;
#pragma unroll
  for (int et = 0; et < 8; ++et) {
#pragma unroll
    for (int r = 0; r < 4; ++r) {
      int e = (we * 8 + et) * 16 + g * 4 + r;
      float wc0 = sWf[e * 3 + 0], wc1 = sWf[e * 3 + 1], wc2 = sWf[e * 3 + 2];
#pragma unroll
      for (int pt = 0; pt < 4; ++pt) {
        float h = fsin(acc[et][pt][r]);
        part[pt][0] = fmaf(h, wc0, part[pt][0]);
        part[pt][1] = fmaf(h, wc1, part[pt][1]);
        part[pt][2] = fmaf(h, wc2, part[pt][2]);
      }
    }
  }
#pragma unroll
  for (int pt = 0; pt < 4; ++pt)
#pragma unroll
    for (int co = 0; co < 3; ++co) {
      float v = part[pt][co];
      v += __shfl_xor(v, 16);
      v += __shfl_xor(v, 32);
      part[pt][co] = v;
    }
  float* sRed = (float*)sH;      // [2 we][256 p][3]
  if (g == 0) {
#pragma unroll
    for (int pt = 0; pt < 4; ++pt) {
      int p = (wp * 4 + pt) * 16 + li;
#pragma unroll
      for (int co = 0; co < 3; ++co)
        sRed[(we * 256 + p) * 3 + co] = part[pt][co];
    }
  }
  __syncthreads();
  float* sFin = (float*)(sH + 8192);
  if (tid < 256) {
    int p = tid;
#pragma unroll
    for (int co = 0; co < 3; ++co)
      sFin[p * 3 + co] =
          (sRed[p * 3 + co] + sRed[(256 + p) * 3 + co] + b_out[co]) * out_scale[co];
  }
  __syncthreads();
  float* op = out + ((size_t)n * HW_S + (size_t)tile * 256) * 3;
  for (int i = tid; i < 768; i += 512) op[i] = sFin[i];
}

extern "C" void kernel_launch(void* const* d_in, const int* in_sizes, int n_in,
                              void* d_out, int out_size, void* d_ws, size_t ws_size,
                              hipStream_t stream) {
  const float* x      = (const float*)d_in[0];
  const float* wo     = (const float*)d_in[1];
  const float* w0     = (const float*)d_in[2];
  const float* b0     = (const float*)d_in[3];
  const float* wsh    = (const float*)d_in[4];
  const float* bsh    = (const float*)d_in[5];
  const float* w_out  = (const float*)d_in[6];
  const float* b_out  = (const float*)d_in[7];
  const float* oscale = (const float*)d_in[8];
  float* out = (float*)d_out;
  char* ws = (char*)d_ws;

  siren_pre<<<1026, 256, 0, stream>>>(wo, w0, b0, wsh, bsh, ws);
  siren_main<<<1024, 512, 0, stream>>>(x, ws, w_out, b_out, oscale, out);
}

// Round 4
// 163.079 us; speedup vs baseline: 1.5351x; 1.1342x over previous
//
#include <hip/hip_runtime.h>

// SIREN hypernetwork, round 4.
// siren_pre: unchanged — W_eff = (ws_h+offset)/2pi, f16, chunk layout
//            [n][l][c(8)][e(256)][k(32)]; a wave's MFMA A-fragment load is
//            1 KiB contiguous from global (L2-resident, sample pinned to XCD).
// siren_main: 2048 blocks = 16 samples x 128 tiles of 128 points, 256 threads
//            (4 waves = e-quarters; per wave et=4 x pt=8, acc=128 VGPR).
//            No W staging in LDS; A-fragments straight from L2. 9 barriers
//            total. Epilogue uses SEPARATE shared arrays (no sH aliasing —
//            round-3's overlayed epilogue diverged under graph replay).
//            LDS 74.5K -> 2 independent blocks/CU.

#define N_S 16
#define HW_S 16384
#define E_S 263936
#define INV2PI 0.15915494309189535f
#define OM2PI  4.774648292756860f   // 30/(2pi)

typedef _Float16 f16x8 __attribute__((ext_vector_type(8)));
typedef _Float16 f16x4 __attribute__((ext_vector_type(4)));
typedef _Float16 f16x2 __attribute__((ext_vector_type(2)));
typedef float f32x4 __attribute__((ext_vector_type(4)));

// ws layout (bytes)
#define WT_OFF   0u          // f16 [16][4][8][256][32]  (8388608 B)
#define W0T_OFF  8388608u    // f32 [16][256][2]  * 30/2pi
#define B0_OFF   8421376u    // f32 [16][256]     * 30/2pi
#define BE_OFF   8437760u    // f32 [16][4][256]  * 1/2pi

__device__ __forceinline__ float fsin(float z) {
  return __builtin_amdgcn_sinf(__builtin_amdgcn_fractf(z));
}

__global__ __launch_bounds__(256) void siren_pre(
    const float* __restrict__ wo, const float* __restrict__ w0,
    const float* __restrict__ b0, const float* __restrict__ wsh,
    const float* __restrict__ bsh, char* __restrict__ ws)
{
  __shared__ float tile[64][65];
  int b = blockIdx.x, t = threadIdx.x;
  if (b < 1024) {
    int n = b >> 6, rem = b & 63, l = rem >> 4, sub = rem & 15;
    int tk = sub >> 2, te = sub & 3;
    int e_loc = t & 63, ksub = t >> 6;
    const float* wo_n = wo + (size_t)n * E_S + 768 + l * 65792;
    const float* wsh_l = wsh + l * 65536;
    for (int r = 0; r < 16; ++r) {
      int k_loc = ksub * 16 + r;
      int k = tk * 64 + k_loc, e = te * 64 + e_loc;
      tile[k_loc][e_loc] = (wsh_l[k * 256 + e] + wo_n[k * 256 + e]) * INV2PI;
    }
    __syncthreads();
    _Float16* wtl = (_Float16*)(ws + WT_OFF) + (size_t)(n * 4 + l) * 65536;
    int kp = (t & 31) * 2, esub = t >> 5;
    for (int r = 0; r < 8; ++r) {
      int e_loc2 = esub * 8 + r;
      f16x2 hv;
      hv[0] = (_Float16)tile[kp][e_loc2];
      hv[1] = (_Float16)tile[kp + 1][e_loc2];
      int e = te * 64 + e_loc2, k = tk * 64 + kp;
      int c = k >> 5, kin = k & 31;
      *(f16x2*)(wtl + (size_t)c * 8192 + e * 32 + kin) = hv;
    }
  } else if (b == 1024) {
    float* w0t = (float*)(ws + W0T_OFF);
    float* b0e = (float*)(ws + B0_OFF);
    for (int idx = t; idx < 4096; idx += 256) {
      int n = idx >> 8, e = idx & 255;
      const float* wo_n = wo + (size_t)n * E_S;
      float2 v;
      v.x = (w0[e] + wo_n[e]) * OM2PI;
      v.y = (w0[256 + e] + wo_n[256 + e]) * OM2PI;
      *(float2*)(w0t + (n * 256 + e) * 2) = v;
      b0e[n * 256 + e] = (b0[e] + wo_n[512 + e]) * OM2PI;
    }
  } else {
    float* be = (float*)(ws + BE_OFF);
    for (int idx = t; idx < 16384; idx += 256) {
      int n = idx >> 10, rem = idx & 1023, l = rem >> 8, e = rem & 255;
      be[(n * 4 + l) * 256 + e] =
          (bsh[l * 256 + e] + wo[(size_t)n * E_S + 768 + l * 65792 + 65536 + e]) * INV2PI;
    }
  }
}

__global__ __launch_bounds__(256, 2) void siren_main(
    const float* __restrict__ x, const char* __restrict__ ws,
    const float* __restrict__ w_out, const float* __restrict__ b_out,
    const float* __restrict__ out_scale, float* __restrict__ out)
{
  __shared__ __align__(16) unsigned char sH[65536];  // H[128 p][256 e] f16, row-XOR-swizzled
  __shared__ float sWf[768];        // w_out [256][3]
  __shared__ float sRed[4][128][3]; // per-wave partials
  __shared__ float sFin[384];       // final [128][3]

  int tid = threadIdx.x;
  int lane = tid & 63, eq = tid >> 6;  // wave = e-quarter
  int g = lane >> 4, li = lane & 15;
  int bid = blockIdx.x;
  int n = bid & 15, tile = bid >> 4;   // sample n -> XCD n&7 (L2 locality)

  const char* wt_n = ws + WT_OFF + (size_t)n * 524288;

  // stage w_out once (read only in epilogue)
  for (int i = tid; i < 768; i += 256) sWf[i] = w_out[i];

  // ---- layer 0 in fp32 (weights pre-scaled by 30/2pi) -> sH
  {
    const float* xp = x + ((size_t)n * HW_S + (size_t)tile * 128) * 2;
    int p = tid & 127;
    float2 xv = *(const float2*)(xp + p * 2);
    const float* w0t = (const float*)(ws + W0T_OFF) + n * 512;
    const float* b0e = (const float*)(ws + B0_OFF) + n * 256;
    int swz = (p & 7) << 4;
    unsigned char* hrow = sH + p * 512;
#pragma unroll
    for (int it = 0; it < 16; ++it) {
      int eg = (tid >> 7) * 16 + it;   // 0..31, wave-uniform
      int e0 = eg * 8;
      f32x4 wa = *(const f32x4*)(w0t + e0 * 2);
      f32x4 wb = *(const f32x4*)(w0t + e0 * 2 + 4);
      f32x4 wc = *(const f32x4*)(w0t + e0 * 2 + 8);
      f32x4 wd = *(const f32x4*)(w0t + e0 * 2 + 12);
      f32x4 ba = *(const f32x4*)(b0e + e0);
      f32x4 bb = *(const f32x4*)(b0e + e0 + 4);
      f16x8 hv;
      hv[0] = (_Float16)fsin(fmaf(xv.y, wa[1], fmaf(xv.x, wa[0], ba[0])));
      hv[1] = (_Float16)fsin(fmaf(xv.y, wa[3], fmaf(xv.x, wa[2], ba[1])));
      hv[2] = (_Float16)fsin(fmaf(xv.y, wb[1], fmaf(xv.x, wb[0], ba[2])));
      hv[3] = (_Float16)fsin(fmaf(xv.y, wb[3], fmaf(xv.x, wb[2], ba[3])));
      hv[4] = (_Float16)fsin(fmaf(xv.y, wc[1], fmaf(xv.x, wc[0], bb[0])));
      hv[5] = (_Float16)fsin(fmaf(xv.y, wc[3], fmaf(xv.x, wc[2], bb[1])));
      hv[6] = (_Float16)fsin(fmaf(xv.y, wd[1], fmaf(xv.x, wd[0], bb[2])));
      hv[7] = (_Float16)fsin(fmaf(xv.y, wd[3], fmaf(xv.x, wd[2], bb[3])));
      *(f16x8*)(hrow + ((eg * 16) ^ swz)) = hv;
    }
  }
  __syncthreads();

  const float* be_n = (const float*)(ws + BE_OFF) + n * 1024;
  int laneoff = (eq * 64 + li) * 64 + g * 16;  // byte offset of lane's W row slice
  f32x4 acc[4][8];

  for (int l = 0; l < 4; ++l) {
    const float* bias = be_n + l * 256;
#pragma unroll
    for (int et = 0; et < 4; ++et) {
      f32x4 bv = *(const f32x4*)(bias + eq * 64 + et * 16 + g * 4);
#pragma unroll
      for (int pt = 0; pt < 8; ++pt) acc[et][pt] = bv;
    }
    const char* wl = wt_n + (size_t)l * 131072 + laneoff;
#pragma unroll
    for (int c = 0; c < 8; ++c) {
      f16x8 afr[4], bfr[8];
#pragma unroll
      for (int et = 0; et < 4; ++et)
        afr[et] = *(const f16x8*)(wl + c * 16384 + et * 1024);
#pragma unroll
      for (int pt = 0; pt < 8; ++pt) {
        int p = pt * 16 + li;
        bfr[pt] = *(const f16x8*)(sH + p * 512 + ((c * 64 + g * 16) ^ ((p & 7) << 4)));
      }
#pragma unroll
      for (int et = 0; et < 4; ++et)
#pragma unroll
        for (int pt = 0; pt < 8; ++pt)
          acc[et][pt] = __builtin_amdgcn_mfma_f32_16x16x32_f16(afr[et], bfr[pt], acc[et][pt], 0, 0, 0);
    }
    if (l < 3) {
      __syncthreads();  // all waves done reading layer-l H
#pragma unroll
      for (int et = 0; et < 4; ++et) {
        int eb = eq * 128 + et * 32 + g * 8;   // byte offset of e*2
#pragma unroll
        for (int pt = 0; pt < 8; ++pt) {
          int p = pt * 16 + li;
          f16x4 hv;
#pragma unroll
          for (int r = 0; r < 4; ++r)
            hv[r] = (_Float16)fsin(acc[et][pt][r]);
          *(f16x4*)(sH + p * 512 + (eb ^ ((p & 7) << 4))) = hv;
        }
      }
      __syncthreads();  // new H visible
    }
  }

  // ---- epilogue: h = sin(acc), out = (h @ w_out + b_out) * out_scale
  float part[8][3];
#pragma unroll
  for (int pt = 0; pt < 8; ++pt)
#pragma unroll
    for (int co = 0; co < 3; ++co) part[pt][co] = 0.f;
#pragma unroll
  for (int et = 0; et < 4; ++et) {
#pragma unroll
    for (int r = 0; r < 4; ++r) {
      int e = eq * 64 + et * 16 + g * 4 + r;
      float wc0 = sWf[e * 3 + 0], wc1 = sWf[e * 3 + 1], wc2 = sWf[e * 3 + 2];
#pragma unroll
      for (int pt = 0; pt < 8; ++pt) {
        float h = fsin(acc[et][pt][r]);
        part[pt][0] = fmaf(h, wc0, part[pt][0]);
        part[pt][1] = fmaf(h, wc1, part[pt][1]);
        part[pt][2] = fmaf(h, wc2, part[pt][2]);
      }
    }
  }
#pragma unroll
  for (int pt = 0; pt < 8; ++pt)
#pragma unroll
    for (int co = 0; co < 3; ++co) {
      float v = part[pt][co];
      v += __shfl_xor(v, 16);
      v += __shfl_xor(v, 32);
      part[pt][co] = v;
    }
  if (g == 0) {
#pragma unroll
    for (int pt = 0; pt < 8; ++pt) {
      int p = pt * 16 + li;
#pragma unroll
      for (int co = 0; co < 3; ++co)
        sRed[eq][p][co] = part[pt][co];
    }
  }
  __syncthreads();
  if (tid < 128) {
    int p = tid;
#pragma unroll
    for (int co = 0; co < 3; ++co)
      sFin[p * 3 + co] = (sRed[0][p][co] + sRed[1][p][co] +
                          sRed[2][p][co] + sRed[3][p][co] +
                          b_out[co]) * out_scale[co];
  }
  __syncthreads();
  float* op = out + ((size_t)n * HW_S + (size_t)tile * 128) * 3;
  for (int i = tid; i < 384; i += 256) op[i] = sFin[i];
}

extern "C" void kernel_launch(void* const* d_in, const int* in_sizes, int n_in,
                              void* d_out, int out_size, void* d_ws, size_t ws_size,
                              hipStream_t stream) {
  const float* x      = (const float*)d_in[0];
  const float* wo     = (const float*)d_in[1];
  const float* w0     = (const float*)d_in[2];
  const float* b0     = (const float*)d_in[3];
  const float* wsh    = (const float*)d_in[4];
  const float* bsh    = (const float*)d_in[5];
  const float* w_out  = (const float*)d_in[6];
  const float* b_out  = (const float*)d_in[7];
  const float* oscale = (const float*)d_in[8];
  float* out = (float*)d_out;
  char* ws = (char*)d_ws;

  siren_pre<<<1026, 256, 0, stream>>>(wo, w0, b0, wsh, bsh, ws);
  siren_main<<<2048, 256, 0, stream>>>(x, ws, w_out, b_out, oscale, out);
}